// Round 1
// baseline (791.796 us; speedup 1.0000x reference)
//
#include <hip/hip_runtime.h>

#define NN 2048
#define DD 64
#define TILE 64
#define LDST 68   // 64 + 4: keeps float4 alignment, breaks pow2 bank pattern

__device__ __forceinline__ float dot4(float4 a, float4 b) {
    return a.x * b.x + a.y * b.y + a.z * b.z + a.w * b.w;
}

__global__ __launch_bounds__(256) void rbf_attn(
    const float* __restrict__ q, const float* __restrict__ k,
    const float* __restrict__ v, float* __restrict__ out)
{
    __shared__ float Qs[TILE][LDST];
    __shared__ float Ks[TILE][LDST];   // reused as P after S-compute
    __shared__ float Vs[TILE][LDST];
    __shared__ float ksq[TILE];

    const int i   = blockIdx.x;        // query tile index
    const int bh  = blockIdx.y;        // batch*head
    const int tid = threadIdx.x;
    const int tx  = tid & 15;
    const int ty  = tid >> 4;
    const size_t base = (size_t)bh * NN * DD;

    // ---- load Q tile (coalesced float4) ----
#pragma unroll
    for (int it = 0; it < 4; ++it) {
        int f   = tid + 256 * it;      // float4 index within 64x64 tile
        int row = f >> 4;
        int c4  = (f & 15) * 4;
        float4 qv = *(const float4*)&q[base + (size_t)(i * TILE + row) * DD + c4];
        *(float4*)&Qs[row][c4] = qv;
    }

    float o[4][4];
    float m[4], l[4];
#pragma unroll
    for (int r = 0; r < 4; ++r) {
        m[r] = -INFINITY; l[r] = 0.f;
#pragma unroll
        for (int c = 0; c < 4; ++c) o[r][c] = 0.f;
    }

    for (int j = 0; j <= i; ++j) {
        __syncthreads();   // A: previous PV done reading Ks(P)/Vs; Q-load drained via B below

        // ---- load K,V tiles + k_sq via shfl reduction ----
#pragma unroll
        for (int it = 0; it < 4; ++it) {
            int f   = tid + 256 * it;
            int row = f >> 4;
            int c4  = (f & 15) * 4;
            size_t g = base + (size_t)(j * TILE + row) * DD + c4;
            float4 kv = *(const float4*)&k[g];
            *(float4*)&Ks[row][c4] = kv;
            float4 vv = *(const float4*)&v[g];
            *(float4*)&Vs[row][c4] = vv;
            float pk = dot4(kv, kv);
            pk += __shfl_xor(pk, 1, 16);
            pk += __shfl_xor(pk, 2, 16);
            pk += __shfl_xor(pk, 4, 16);
            pk += __shfl_xor(pk, 8, 16);
            if ((tid & 15) == 0) ksq[row] = pk;
        }
        __syncthreads();   // B: tiles + ksq ready (also covers Q on first iter)

        // ---- S = Q K^T  (4x4 register tile, float4 over d) ----
        float s[4][4] = {{0.f}};
#pragma unroll
        for (int d0 = 0; d0 < DD; d0 += 4) {
            float4 qv[4], kv[4];
#pragma unroll
            for (int r = 0; r < 4; ++r) qv[r] = *(const float4*)&Qs[4 * ty + r][d0];
#pragma unroll
            for (int c = 0; c < 4; ++c) kv[c] = *(const float4*)&Ks[4 * tx + c][d0];
#pragma unroll
            for (int r = 0; r < 4; ++r)
#pragma unroll
                for (int c = 0; c < 4; ++c)
                    s[r][c] += dot4(qv[r], kv[c]);
        }
        float kk[4];
#pragma unroll
        for (int c = 0; c < 4; ++c) kk[c] = ksq[4 * tx + c];

        // ---- logits + causal mask + online softmax ----
        // reference: logits = -(q2 + k2 - 2qk)*scale ; -q2*scale is row-const
        // (cancels in softmax), relu clips only fp noise -> dropped.
        float p[4][4];
        const bool diag = (j == i);
#pragma unroll
        for (int r = 0; r < 4; ++r) {
            float lg[4];
#pragma unroll
            for (int c = 0; c < 4; ++c) {
                float lgv = (2.f * s[r][c] - kk[c]) * 0.125f;
                if (diag && (4 * tx + c) > (4 * ty + r)) lgv = -INFINITY;
                lg[c] = lgv;
            }
            float mx = fmaxf(fmaxf(lg[0], lg[1]), fmaxf(lg[2], lg[3]));
            mx = fmaxf(mx, __shfl_xor(mx, 1, 16));
            mx = fmaxf(mx, __shfl_xor(mx, 2, 16));
            mx = fmaxf(mx, __shfl_xor(mx, 4, 16));
            mx = fmaxf(mx, __shfl_xor(mx, 8, 16));
            float mnew  = fmaxf(m[r], mx);
            float alpha = __expf(m[r] - mnew);
            float ls = 0.f;
#pragma unroll
            for (int c = 0; c < 4; ++c) {
                p[r][c] = __expf(lg[c] - mnew);
                ls += p[r][c];
            }
            ls += __shfl_xor(ls, 1, 16);
            ls += __shfl_xor(ls, 2, 16);
            ls += __shfl_xor(ls, 4, 16);
            ls += __shfl_xor(ls, 8, 16);
            l[r] = l[r] * alpha + ls;
            m[r] = mnew;
#pragma unroll
            for (int c = 0; c < 4; ++c) o[r][c] *= alpha;
        }

        __syncthreads();   // C: everyone done reading Ks
#pragma unroll
        for (int r = 0; r < 4; ++r)
            *(float4*)&Ks[4 * ty + r][4 * tx] =
                make_float4(p[r][0], p[r][1], p[r][2], p[r][3]);
        __syncthreads();   // D: P ready in Ks

        // ---- O += P V ----
#pragma unroll
        for (int k0 = 0; k0 < TILE; k0 += 4) {
            float4 pv[4], vv[4];
#pragma unroll
            for (int r = 0; r < 4; ++r) pv[r] = *(const float4*)&Ks[4 * ty + r][k0];
#pragma unroll
            for (int t = 0; t < 4; ++t) vv[t] = *(const float4*)&Vs[k0 + t][4 * tx];
#pragma unroll
            for (int r = 0; r < 4; ++r) {
                o[r][0] += pv[r].x * vv[0].x + pv[r].y * vv[1].x + pv[r].z * vv[2].x + pv[r].w * vv[3].x;
                o[r][1] += pv[r].x * vv[0].y + pv[r].y * vv[1].y + pv[r].z * vv[2].y + pv[r].w * vv[3].y;
                o[r][2] += pv[r].x * vv[0].z + pv[r].y * vv[1].z + pv[r].z * vv[2].z + pv[r].w * vv[3].z;
                o[r][3] += pv[r].x * vv[0].w + pv[r].y * vv[1].w + pv[r].z * vv[2].w + pv[r].w * vv[3].w;
            }
        }
    }

    // ---- epilogue: normalize + store ----
#pragma unroll
    for (int r = 0; r < 4; ++r) {
        float inv = 1.0f / l[r];
        float4 ov = make_float4(o[r][0] * inv, o[r][1] * inv,
                                o[r][2] * inv, o[r][3] * inv);
        *(float4*)&out[base + (size_t)(i * TILE + 4 * ty + r) * DD + 4 * tx] = ov;
    }
}

extern "C" void kernel_launch(void* const* d_in, const int* in_sizes, int n_in,
                              void* d_out, int out_size, void* d_ws, size_t ws_size,
                              hipStream_t stream) {
    (void)in_sizes; (void)n_in; (void)out_size; (void)d_ws; (void)ws_size;
    const float* q = (const float*)d_in[0];
    const float* k = (const float*)d_in[1];
    const float* v = (const float*)d_in[2];
    float* out     = (float*)d_out;
    dim3 grid(NN / TILE, 2 * 16);   // 32 q-tiles x 32 batch-heads
    rbf_attn<<<grid, 256, 0, stream>>>(q, k, v, out);
}

// Round 2
// 184.871 us; speedup vs baseline: 4.2830x; 4.2830x over previous
//
#include <hip/hip_runtime.h>

#define BHN 32          // B*H
#define NN 2048
#define DD 64
#define LDH 72          // f16 LDS stride: 144B rows -> conflict-free b128 frags
#define C1 0.36067376f  // 2/sqrt(D) * log2(e) = 0.25*1.442695
#define C1H 0.18033688f // C1/2

typedef _Float16 h8 __attribute__((ext_vector_type(8)));
typedef _Float16 h4 __attribute__((ext_vector_type(4)));
typedef float f32x16 __attribute__((ext_vector_type(16)));

// ---- prep 1: Kh = f16(K), hk = 0.5*C1*||k||^2  (4 threads per row) ----
__global__ __launch_bounds__(256) void prep_k(const float* __restrict__ k,
                                              _Float16* __restrict__ Kh,
                                              float* __restrict__ hk) {
    int gid = blockIdx.x * 256 + threadIdx.x;   // 262144 = 65536 rows * 4
    int row = gid >> 2;
    int part = gid & 3;
    const float* src = k + (size_t)row * DD + part * 16;
    float s = 0.f;
#pragma unroll
    for (int t = 0; t < 4; ++t) {
        float4 a = *(const float4*)&src[4 * t];
        h4 hv = {(_Float16)a.x, (_Float16)a.y, (_Float16)a.z, (_Float16)a.w};
        *(h4*)&Kh[(size_t)row * DD + part * 16 + 4 * t] = hv;
        s += a.x * a.x + a.y * a.y + a.z * a.z + a.w * a.w;
    }
    s += __shfl_xor(s, 1);
    s += __shfl_xor(s, 2);
    if (part == 0) hk[row] = s * C1H;
}

// ---- prep 2: Vt[bh][d][n] = f16(V[bh][n][d])  (LDS tile transpose) ----
__global__ __launch_bounds__(128) void prep_v(const float* __restrict__ v,
                                              _Float16* __restrict__ Vt) {
    __shared__ _Float16 T[64][LDH];
    int kb = blockIdx.x, bh = blockIdx.y, tid = threadIdx.x;
    size_t ibase = (size_t)bh * (NN * DD) + (size_t)kb * 64 * DD;
#pragma unroll
    for (int it = 0; it < 8; ++it) {
        int f = tid + 128 * it;
        int key = f >> 4;
        int c4 = (f & 15) * 4;
        float4 a = *(const float4*)&v[ibase + (size_t)key * DD + c4];
        h4 hv = {(_Float16)a.x, (_Float16)a.y, (_Float16)a.z, (_Float16)a.w};
        *(h4*)&T[key][c4] = hv;
    }
    __syncthreads();
    size_t obase = (size_t)bh * (DD * NN) + (size_t)kb * 64;
#pragma unroll
    for (int it = 0; it < 4; ++it) {
        int f = tid + 128 * it;
        int d = f >> 3;
        int k8 = (f & 7) * 8;
        h8 o;
#pragma unroll
        for (int t = 0; t < 8; ++t) o[t] = T[k8 + t][d];
        *(h8*)&Vt[obase + (size_t)d * NN + k8] = o;
    }
}

// ---- main: flash RBF attention, 32x32x16 f16 MFMA, static-max softmax ----
__global__ __launch_bounds__(128, 3) void rbf_attn(
    const float* __restrict__ q, const _Float16* __restrict__ Kh,
    const _Float16* __restrict__ Vt, const float* __restrict__ hk,
    float* __restrict__ out)
{
    __shared__ _Float16 QP[64][LDH];   // Q tile, reused as P (wave-private rows)
    __shared__ _Float16 Ks[64][LDH];

    const int tid = threadIdx.x;
    const int bh = blockIdx.x;         // fast dim -> i spread across CUs
    const int i  = blockIdx.y;
    const int lane = tid & 63, wv = tid >> 6;
    const int ln31 = lane & 31, lh = lane >> 5;
    const size_t fbase = (size_t)bh * (NN * DD);

    // stage Q tile (f32 -> f16)
#pragma unroll
    for (int it = 0; it < 8; ++it) {
        int f = tid + 128 * it;
        int row = f >> 4;
        int c4 = (f & 15) * 4;
        float4 a = *(const float4*)&q[fbase + (size_t)(i * 64 + row) * DD + c4];
        h4 hv = {(_Float16)a.x, (_Float16)a.y, (_Float16)a.z, (_Float16)a.w};
        *(h4*)&QP[row][c4] = hv;
    }
    __syncthreads();

    // Q A-frags: A[m=ln31][k=lh*8+j], wave wv owns rows 32*wv..+31
    h8 qf[4];
#pragma unroll
    for (int c = 0; c < 4; ++c) qf[c] = *(h8*)&QP[32 * wv + ln31][16 * c + lh * 8];

    f32x16 O0, O1;
    float lsum[16];
#pragma unroll
    for (int r = 0; r < 16; ++r) { O0[r] = 0.f; O1[r] = 0.f; lsum[r] = 0.f; }

    const _Float16* vb = Vt + (size_t)bh * (DD * NN);
    const _Float16* kb = Kh + fbase;
    const float* hkb = hk + bh * NN;

    for (int j = 0; j <= i; ++j) {
        __syncthreads();   // prior tile's K-frag reads complete
        // stage K tile (f16 copy, conflict-free b128 in/out)
#pragma unroll
        for (int it = 0; it < 4; ++it) {
            int f = tid + 128 * it;
            int row = f >> 3;
            int c8 = (f & 7) * 8;
            h8 kv = *(const h8*)&kb[(size_t)(j * 64 + row) * DD + c8];
            *(h8*)&Ks[row][c8] = kv;
        }
        float hk0 = hkb[j * 64 + ln31];
        float hk1 = hkb[j * 64 + 32 + ln31];
        // V B-frags direct from pre-transposed global (early issue; no barrier dep)
        h8 vf[2][4];
#pragma unroll
        for (int nh = 0; nh < 2; ++nh)
#pragma unroll
            for (int c = 0; c < 4; ++c)
                vf[nh][c] = *(const h8*)&vb[(size_t)(32 * nh + ln31) * NN + j * 64 + 16 * c + lh * 8];
        __syncthreads();   // K tile ready

        // S = Q K^T  (two 32x32 C-frags: keys 0..31, 32..63)
        f32x16 S0, S1;
#pragma unroll
        for (int r = 0; r < 16; ++r) { S0[r] = 0.f; S1[r] = 0.f; }
#pragma unroll
        for (int c = 0; c < 4; ++c) {
            h8 kf0 = *(h8*)&Ks[ln31][16 * c + lh * 8];
            h8 kf1 = *(h8*)&Ks[32 + ln31][16 * c + lh * 8];
            S0 = __builtin_amdgcn_mfma_f32_32x32x16_f16(qf[c], kf0, S0, 0, 0, 0);
            S1 = __builtin_amdgcn_mfma_f32_32x32x16_f16(qf[c], kf1, S1, 0, 0, 0);
        }

        // p = exp2(s*C1 - hk)  — true logits <= q^2/8: row-constant factor
        // cancels in p/l, no running max / rescale needed. relu clips only
        // fp noise (|err| ~1e-3 in logits) -> dropped.
        const bool diag = (j == i);
#pragma unroll
        for (int r = 0; r < 16; ++r) {
            int rowt = 32 * wv + 4 * lh + (r & 3) + 8 * (r >> 2); // C/D row map
            float p0 = __builtin_amdgcn_exp2f(fmaf(S0[r], C1, -hk0));
            float p1 = __builtin_amdgcn_exp2f(fmaf(S1[r], C1, -hk1));
            if (diag) {
                if (ln31 > rowt) p0 = 0.f;
                if (32 + ln31 > rowt) p1 = 0.f;
            }
            lsum[r] += p0 + p1;
            QP[rowt][ln31] = (_Float16)p0;        // C-layout -> A-layout via LDS
            QP[rowt][32 + ln31] = (_Float16)p1;   // (wave-private rows)
        }

        // O += P V   (P A-frags from LDS, V B-frags from regs)
#pragma unroll
        for (int c = 0; c < 4; ++c) {
            h8 pf = *(h8*)&QP[32 * wv + ln31][16 * c + lh * 8];
            O0 = __builtin_amdgcn_mfma_f32_32x32x16_f16(pf, vf[0][c], O0, 0, 0, 0);
            O1 = __builtin_amdgcn_mfma_f32_32x32x16_f16(pf, vf[1][c], O1, 0, 0, 0);
        }
    }

    // epilogue: reduce l across the 32 row-mate lanes, normalize, store
#pragma unroll
    for (int r = 0; r < 16; ++r) {
        float l = lsum[r];
        l += __shfl_xor(l, 1);
        l += __shfl_xor(l, 2);
        l += __shfl_xor(l, 4);
        l += __shfl_xor(l, 8);
        l += __shfl_xor(l, 16);
        float inv = 1.f / l;
        int rowt = 32 * wv + 4 * lh + (r & 3) + 8 * (r >> 2);
        size_t ro = fbase + (size_t)(i * 64 + rowt) * DD;
        out[ro + ln31] = O0[r] * inv;
        out[ro + 32 + ln31] = O1[r] * inv;
    }
}

extern "C" void kernel_launch(void* const* d_in, const int* in_sizes, int n_in,
                              void* d_out, int out_size, void* d_ws, size_t ws_size,
                              hipStream_t stream) {
    (void)in_sizes; (void)n_in; (void)out_size;
    const float* q = (const float*)d_in[0];
    const float* k = (const float*)d_in[1];
    const float* v = (const float*)d_in[2];
    float* out = (float*)d_out;

    // ws: [hk 256KB][Kh 8MB f16][Vt 8MB f16] = ~16.3MB
    float* hk = (float*)d_ws;
    _Float16* Kh = (_Float16*)((char*)d_ws + 262144);
    _Float16* Vt = (_Float16*)((char*)d_ws + 262144 + 8388608);
    (void)ws_size;

    prep_k<<<1024, 256, 0, stream>>>(k, Kh, hk);
    prep_v<<<dim3(32, 32), 128, 0, stream>>>(v, Vt);
    rbf_attn<<<dim3(32, 32), 128, 0, stream>>>(q, Kh, Vt, hk, out);
}

// Round 4
// 149.199 us; speedup vs baseline: 5.3070x; 1.2391x over previous
//
#include <hip/hip_runtime.h>

#define NN 2048
#define DD 64
#define LDH 72          // f16 LDS stride (144 B rows) — 0 bank conflicts measured in R2
#define C1 0.36067376f  // 2/sqrt(D) * log2(e)
#define C1H 0.18033688f // C1/2

typedef _Float16 h8 __attribute__((ext_vector_type(8)));
typedef _Float16 h4 __attribute__((ext_vector_type(4)));
typedef _Float16 h2 __attribute__((ext_vector_type(2)));
typedef float f32x16 __attribute__((ext_vector_type(16)));

union U32H2 { unsigned u; h2 h; };
union H8U4 { h8 v; unsigned u[4]; };

// ---- fused prep: Kh=f16(K), hk=C1H*||k||^2, Vt[bh][d][n]=f16(V[bh][n][d]) ----
__global__ __launch_bounds__(256) void prep(const float* __restrict__ k,
                                            const float* __restrict__ v,
                                            _Float16* __restrict__ Kh,
                                            float* __restrict__ hk,
                                            _Float16* __restrict__ Vt) {
    __shared__ _Float16 T[64][LDH];
    const int kb = blockIdx.x, bh = blockIdx.y, tid = threadIdx.x;
    const size_t ibase = (size_t)bh * (NN * DD) + (size_t)kb * 64 * DD;
    { // K phase: 4 threads per row
        int row = tid >> 2, part = tid & 3;
        const float* src = k + ibase + (size_t)row * DD + part * 16;
        float s = 0.f;
#pragma unroll
        for (int t = 0; t < 4; ++t) {
            float4 a = *(const float4*)&src[4 * t];
            h4 hv = {(_Float16)a.x, (_Float16)a.y, (_Float16)a.z, (_Float16)a.w};
            *(h4*)&Kh[ibase + (size_t)row * DD + part * 16 + 4 * t] = hv;
            s += a.x * a.x + a.y * a.y + a.z * a.z + a.w * a.w;
        }
        s += __shfl_xor(s, 1);
        s += __shfl_xor(s, 2);
        if (part == 0) hk[bh * NN + kb * 64 + row] = s * C1H;
    }
    // V phase: tile -> LDS f16 -> transposed store
#pragma unroll
    for (int it = 0; it < 4; ++it) {
        int f = tid + 256 * it;
        int row = f >> 4, c4 = (f & 15) * 4;
        float4 a = *(const float4*)&v[ibase + (size_t)row * DD + c4];
        h4 hv = {(_Float16)a.x, (_Float16)a.y, (_Float16)a.z, (_Float16)a.w};
        *(h4*)&T[row][c4] = hv;
    }
    __syncthreads();
    const size_t obase = (size_t)bh * (DD * NN) + (size_t)kb * 64;
#pragma unroll
    for (int it = 0; it < 2; ++it) {
        int f = tid + 256 * it;
        int d = f >> 3, k8 = (f & 7) * 8;
        h8 o;
#pragma unroll
        for (int t = 0; t < 8; ++t) o[t] = T[k8 + t][d];
        *(h8*)&Vt[obase + (size_t)d * NN + k8] = o;
    }
}

// ---- main: S^T orientation, per-lane online softmax, shuffle P transform ----
__global__ __launch_bounds__(128, 2) void rbf_attn(
    const float* __restrict__ q, const _Float16* __restrict__ Kh,
    const _Float16* __restrict__ Vt, const float* __restrict__ hk,
    float* __restrict__ out)
{
    __shared__ _Float16 KB[2][64][LDH];

    const int tid = threadIdx.x;
    const int bh = blockIdx.x;
    const int i  = 31 - blockIdx.y;    // LPT: heaviest q-tiles dispatch first
    const int lane = tid & 63, wv = tid >> 6;
    const int ln31 = lane & 31, lh = lane >> 5;
    const size_t fbase = (size_t)bh * (NN * DD);
    const _Float16* kbase = Kh + fbase;
    const _Float16* vb = Vt + (size_t)bh * (DD * NN);
    const float4* hk4 = (const float4*)(hk + bh * NN);

    // stage Q -> KB[1] (f32->f16) and K tile 0 -> KB[0]
#pragma unroll
    for (int it = 0; it < 8; ++it) {
        int f = tid + 128 * it;
        int row = f >> 4, c4 = (f & 15) * 4;
        float4 a = *(const float4*)&q[fbase + (size_t)(i * 64 + row) * DD + c4];
        h4 hv = {(_Float16)a.x, (_Float16)a.y, (_Float16)a.z, (_Float16)a.w};
        *(h4*)&KB[1][row][c4] = hv;
    }
#pragma unroll
    for (int it = 0; it < 4; ++it) {
        int f = tid + 128 * it;
        int row = f >> 3, c8 = (f & 7) * 8;
        *(h8*)&KB[0][row][c8] = *(const h8*)&kbase[(size_t)row * DD + c8];
    }
    __syncthreads();

    const int qloc = 32 * wv + ln31;   // this lane's query (local)
    h8 qf[4];                          // Q as B-frags (per-lane col = query)
#pragma unroll
    for (int c = 0; c < 4; ++c) qf[c] = *(h8*)&KB[1][qloc][16 * c + 8 * lh];
    __syncthreads();                   // qf reads done before tile-1 staging

    f32x16 O0, O1;                     // O^T frags: rows d 0..31 / 32..63, col=query
#pragma unroll
    for (int r = 0; r < 16; ++r) { O0[r] = 0.f; O1[r] = 0.f; }
    float lsum = 0.f;
    float mrun = -INFINITY;            // per-lane running max of logits (log2 units)

    for (int j = 0; j <= i; ++j) {
        const int cur = j & 1;
        const bool diag = (j == i);
        const bool more = (j < i);
        const int nf = (diag && wv == 0) ? 1 : 2;  // f=1 frag fully masked for wv0

        // --- early global issues: K prefetch, V slices (max latency slack) ---
        h8 kst[4];
        if (more) {
#pragma unroll
            for (int it = 0; it < 4; ++it) {
                int f = tid + 128 * it;
                int row = f >> 3, c8 = (f & 7) * 8;
                kst[it] = *(const h8*)&kbase[(size_t)((j + 1) * 64 + row) * DD + c8];
            }
        }
        h8 vA[4], vB[4];
#pragma unroll
        for (int t = 0; t < 4; ++t) {
            vA[t] = *(const h8*)&vb[(size_t)ln31 * NN + j * 64 + 16 * t + 8 * lh];
            vB[t] = *(const h8*)&vb[(size_t)(32 + ln31) * NN + j * 64 + 16 * t + 8 * lh];
        }

        // --- S^T = K Q^T ---
        f32x16 S0, S1;
#pragma unroll
        for (int r = 0; r < 16; ++r) { S0[r] = 0.f; S1[r] = 0.f; }
#pragma unroll
        for (int c = 0; c < 4; ++c) {
            h8 kf0 = *(h8*)&KB[cur][ln31][16 * c + 8 * lh];
            S0 = __builtin_amdgcn_mfma_f32_32x32x16_f16(kf0, qf[c], S0, 0, 0, 0);
        }
        if (nf == 2) {
#pragma unroll
            for (int c = 0; c < 4; ++c) {
                h8 kf1 = *(h8*)&KB[cur][32 + ln31][16 * c + 8 * lh];
                S1 = __builtin_amdgcn_mfma_f32_32x32x16_f16(kf1, qf[c], S1, 0, 0, 0);
            }
        }

        // --- x = s*C1 - hk (log2 logits, per-key), causal mask ---
#pragma unroll
        for (int g = 0; g < 4; ++g) {
            float4 h0 = hk4[j * 16 + lh + 2 * g];
            const float* h0f = (const float*)&h0;
#pragma unroll
            for (int e = 0; e < 4; ++e) {
                int r = 4 * g + e;
                float x = fmaf(S0[r], C1, -h0f[e]);
                if (diag) {
                    int keyloc = e + 8 * g + 4 * lh;
                    if (keyloc > qloc) x = -INFINITY;
                }
                S0[r] = x;
            }
        }
        if (nf == 2) {
#pragma unroll
            for (int g = 0; g < 4; ++g) {
                float4 h1 = hk4[j * 16 + 8 + lh + 2 * g];
                const float* h1f = (const float*)&h1;
#pragma unroll
                for (int e = 0; e < 4; ++e) {
                    int r = 4 * g + e;
                    float x = fmaf(S1[r], C1, -h1f[e]);
                    if (diag) {
                        int keyloc = 32 + e + 8 * g + 4 * lh;
                        if (keyloc > qloc) x = -INFINITY;
                    }
                    S1[r] = x;
                }
            }
        }

        // --- online max (per-lane scalar: col=lane=query) ---
        float mt = S0[0];
#pragma unroll
        for (int r = 1; r < 16; ++r) mt = fmaxf(mt, S0[r]);
        if (nf == 2) {
#pragma unroll
            for (int r = 0; r < 16; ++r) mt = fmaxf(mt, S1[r]);
        }
        mt = fmaxf(mt, __shfl_xor(mt, 32));     // partner covers complementary keys
        float mnew = fmaxf(mrun, mt);
        float alpha = __builtin_amdgcn_exp2f(mrun - mnew);  // exp2(-inf)=0 first tile
        mrun = mnew;
        lsum *= alpha;
#pragma unroll
        for (int r = 0; r < 16; ++r) { O0[r] *= alpha; O1[r] *= alpha; }

        // --- p = exp2(x - m) in [0,1]: ideal f16 range, no underflow pathology ---
#pragma unroll
        for (int r = 0; r < 16; ++r) {
            float p = __builtin_amdgcn_exp2f(S0[r] - mnew);
            S0[r] = p; lsum += p;
        }
        if (nf == 2) {
#pragma unroll
            for (int r = 0; r < 16; ++r) {
                float p = __builtin_amdgcn_exp2f(S1[r] - mnew);
                S1[r] = p; lsum += p;
            }
        }

        // --- per f-block: pack f16, lane^32 exchange C->B frag, PV MFMAs ---
#pragma unroll
        for (int f = 0; f < 2; ++f) {
            if (f == 1 && nf == 1) break;
            unsigned pk[8];
#pragma unroll
            for (int hh = 0; hh < 8; ++hh) {
                float a = (f == 0) ? S0[2 * hh] : S1[2 * hh];
                float b = (f == 0) ? S0[2 * hh + 1] : S1[2 * hh + 1];
                U32H2 t; t.h = h2{(_Float16)a, (_Float16)b};
                pk[hh] = t.u;
            }
#pragma unroll
            for (int s = 0; s < 2; ++s) {
                unsigned send0 = lh ? pk[4 * s + 0] : pk[4 * s + 2];
                unsigned send1 = lh ? pk[4 * s + 1] : pk[4 * s + 3];
                unsigned r0 = (unsigned)__shfl_xor((int)send0, 32);
                unsigned r1 = (unsigned)__shfl_xor((int)send1, 32);
                H8U4 pb;
                pb.u[0] = lh ? r0 : pk[4 * s + 0];
                pb.u[1] = lh ? r1 : pk[4 * s + 1];
                pb.u[2] = lh ? pk[4 * s + 2] : r0;
                pb.u[3] = lh ? pk[4 * s + 3] : r1;
                int t = 2 * f + s;
                O0 = __builtin_amdgcn_mfma_f32_32x32x16_f16(vA[t], pb.v, O0, 0, 0, 0);
                O1 = __builtin_amdgcn_mfma_f32_32x32x16_f16(vB[t], pb.v, O1, 0, 0, 0);
            }
        }

        if (more) {   // stage prefetched K tile (after-barrier-safe dbuf)
#pragma unroll
            for (int it = 0; it < 4; ++it) {
                int f = tid + 128 * it;
                int row = f >> 3, c8 = (f & 7) * 8;
                *(h8*)&KB[cur ^ 1][row][c8] = kst[it];
            }
        }
        __syncthreads();
    }

    // epilogue: l = own + partner(lane^32); normalized float4 stores
    float lt = lsum + __shfl_xor(lsum, 32);
    float inv = 1.f / lt;
    size_t ro = fbase + (size_t)(i * 64 + qloc) * DD;
#pragma unroll
    for (int g = 0; g < 4; ++g) {
        float4 o0 = make_float4(O0[4 * g + 0] * inv, O0[4 * g + 1] * inv,
                                O0[4 * g + 2] * inv, O0[4 * g + 3] * inv);
        *(float4*)&out[ro + 8 * g + 4 * lh] = o0;
        float4 o1 = make_float4(O1[4 * g + 0] * inv, O1[4 * g + 1] * inv,
                                O1[4 * g + 2] * inv, O1[4 * g + 3] * inv);
        *(float4*)&out[ro + 32 + 8 * g + 4 * lh] = o1;
    }
}

extern "C" void kernel_launch(void* const* d_in, const int* in_sizes, int n_in,
                              void* d_out, int out_size, void* d_ws, size_t ws_size,
                              hipStream_t stream) {
    (void)in_sizes; (void)n_in; (void)out_size; (void)ws_size;
    const float* q = (const float*)d_in[0];
    const float* k = (const float*)d_in[1];
    const float* v = (const float*)d_in[2];
    float* out = (float*)d_out;

    // ws: [hk 256KB][Kh 8MB f16][Vt 8MB f16]
    float* hk = (float*)d_ws;
    _Float16* Kh = (_Float16*)((char*)d_ws + 262144);
    _Float16* Vt = (_Float16*)((char*)d_ws + 262144 + 8388608);

    prep<<<dim3(32, 32), 256, 0, stream>>>(k, v, Kh, hk, Vt);
    rbf_attn<<<dim3(32, 32), 128, 0, stream>>>(q, Kh, Vt, hk, out);
}

// Round 5
// 137.107 us; speedup vs baseline: 5.7750x; 1.0882x over previous
//
#include <hip/hip_runtime.h>

#define NN 2048
#define DD 64
#define C1 0.36067376f  // 2/sqrt(D) * log2(e)
#define C1H 0.18033688f // C1/2

typedef _Float16 h8 __attribute__((ext_vector_type(8)));
typedef _Float16 h4 __attribute__((ext_vector_type(4)));
typedef float f32x16 __attribute__((ext_vector_type(16)));

union H8U4 { h8 v; unsigned u[4]; };

// ---- prep: frag-major swizzles so the main loop is pure coalesced loads ----
// Ks[bh][jj][c][lh][ln]{8}  = K[32jj+ln][16c+8lh+0..7]          (A-frag order)
// Vs[bh][jj][o][c][lh][ln]{8}= V[32jj+16c+8lh+j][32o+ln]        (V^T A-frag order)
// hk[bh][n] = C1H*||k_n||^2
__global__ __launch_bounds__(64) void prep(const float* __restrict__ k,
                                           const float* __restrict__ v,
                                           _Float16* __restrict__ Ks,
                                           _Float16* __restrict__ Vs,
                                           float* __restrict__ hk) {
    __shared__ _Float16 T[32][72];
    const int jj = blockIdx.x, bh = blockIdx.y, lane = threadIdx.x;
    const int ln = lane & 31, lh = lane >> 5;
    const size_t ibase = (size_t)bh * NN * DD + (size_t)jj * 32 * DD;

    { // K frags + row sumsq (lh halves cover complementary d-ranges)
        const float* kr = k + ibase + (size_t)ln * DD;
        float s = 0.f;
#pragma unroll
        for (int c = 0; c < 4; ++c) {
            float4 a = *(const float4*)&kr[16 * c + 8 * lh];
            float4 b = *(const float4*)&kr[16 * c + 8 * lh + 4];
            h8 o = {(_Float16)a.x, (_Float16)a.y, (_Float16)a.z, (_Float16)a.w,
                    (_Float16)b.x, (_Float16)b.y, (_Float16)b.z, (_Float16)b.w};
            *(h8*)&Ks[((size_t)bh * 16384 + jj * 256 + c * 64 + lh * 32 + ln) * 8] = o;
            s += a.x*a.x + a.y*a.y + a.z*a.z + a.w*a.w
               + b.x*b.x + b.y*b.y + b.z*b.z + b.w*b.w;
        }
        s += __shfl_xor(s, 32);
        if (lh == 0) hk[bh * NN + jj * 32 + ln] = s * C1H;
    }

    // V tile -> LDS f16 -> transposed frag-major store
#pragma unroll
    for (int t = 0; t < 8; ++t) {
        int f = lane + 64 * t;            // 512 float4 groups = 32 rows x 16
        int row = f >> 4, c4 = (f & 15) * 4;
        float4 a = *(const float4*)&v[ibase + (size_t)row * DD + c4];
        h4 hv = {(_Float16)a.x, (_Float16)a.y, (_Float16)a.z, (_Float16)a.w};
        *(h4*)&T[row][c4] = hv;
    }
    __syncthreads();
#pragma unroll
    for (int oc = 0; oc < 4; ++oc) {
        int o = oc >> 1, c = oc & 1;
        h8 r;
#pragma unroll
        for (int jx = 0; jx < 8; ++jx) r[jx] = T[16 * c + 8 * lh + jx][32 * o + ln];
        *(h8*)&Vs[((size_t)bh * 16384 + jj * 256 + o * 128 + c * 64 + lh * 32 + ln) * 8] = r;
    }
}

// ---- main: barrier-free, LDS-free, register-pipelined flash RBF ----
__global__ __launch_bounds__(128, 2) void rbf_attn(
    const float* __restrict__ q, const _Float16* __restrict__ Ks,
    const _Float16* __restrict__ Vs, const float* __restrict__ hk,
    float* __restrict__ out)
{
    const int tid = threadIdx.x;
    const int bh = blockIdx.x;
    const int qb = 31 - blockIdx.y;      // LPT: heaviest blocks dispatch first
    const int wv = tid >> 6, lane = tid & 63;
    const int ln = lane & 31, lh = lane >> 5;
    const int jmax = 2 * qb + wv;        // this wave's diagonal 32-key tile
    const int qrow = qb * 64 + wv * 32 + ln;
    const size_t fbase = (size_t)bh * NN * DD;

    // Q B-frags straight from global f32 (per-lane 16B-contiguous, L2-hot)
    h8 qf[4];
    {
        const float* qr = q + fbase + (size_t)qrow * DD;
#pragma unroll
        for (int c = 0; c < 4; ++c) {
            float4 a = *(const float4*)&qr[16 * c + 8 * lh];
            float4 b = *(const float4*)&qr[16 * c + 8 * lh + 4];
            qf[c] = h8{(_Float16)a.x, (_Float16)a.y, (_Float16)a.z, (_Float16)a.w,
                       (_Float16)b.x, (_Float16)b.y, (_Float16)b.z, (_Float16)b.w};
        }
    }

    const _Float16* Ksb = Ks + (size_t)bh * 131072;
    const _Float16* Vsb = Vs + (size_t)bh * 131072;
    const float4* hk4 = (const float4*)(hk + bh * NN);
    const int klq = (lh * 32 + ln) * 8;  // element offset of this lane's frag

    f32x16 O0, O1;
#pragma unroll
    for (int r = 0; r < 16; ++r) { O0[r] = 0.f; O1[r] = 0.f; }
    float lsum = 0.f, mrun = -INFINITY;

    auto loadT = [&](int jj, h8 (&kf)[4], h8 (&vf)[4], float4 (&hr)[4]) {
        const _Float16* kp = Ksb + (size_t)jj * 2048 + klq;
        const _Float16* vp = Vsb + (size_t)jj * 2048 + klq;
#pragma unroll
        for (int c = 0; c < 4; ++c) kf[c] = *(const h8*)(kp + c * 512);
#pragma unroll
        for (int oc = 0; oc < 4; ++oc)
            vf[oc] = *(const h8*)(vp + (oc >> 1) * 1024 + (oc & 1) * 512);
#pragma unroll
        for (int g = 0; g < 4; ++g) hr[g] = hk4[jj * 8 + g * 2 + lh];
    };

    auto comp = [&](int jj, h8 (&kf)[4], h8 (&vf)[4], float4 (&hr)[4]) {
        f32x16 S;
#pragma unroll
        for (int r = 0; r < 16; ++r) S[r] = 0.f;
#pragma unroll
        for (int c = 0; c < 4; ++c)
            S = __builtin_amdgcn_mfma_f32_32x32x16_f16(kf[c], qf[c], S, 0, 0, 0);

        const bool diag = (jj == jmax);
        float x[16];
#pragma unroll
        for (int r = 0; r < 16; ++r) {
            const float* hf = (const float*)&hr[r >> 2];
            float xv = fmaf(S[r], C1, -hf[r & 3]);
            if (diag) {
                int keyloc = (r & 3) + 8 * (r >> 2) + 4 * lh;
                if (keyloc > ln) xv = -INFINITY;
            }
            x[r] = xv;
        }
        float mt = x[0];
#pragma unroll
        for (int r = 1; r < 16; ++r) mt = fmaxf(mt, x[r]);
        mt = fmaxf(mt, __shfl_xor(mt, 32));
        float mnew = fmaxf(mrun, mt);
        float alpha = __builtin_amdgcn_exp2f(mrun - mnew);
        mrun = mnew;
        float p[16], ps = 0.f;
#pragma unroll
        for (int r = 0; r < 16; ++r) {
            p[r] = __builtin_amdgcn_exp2f(x[r] - mnew);
            ps += p[r];
        }
        lsum = fmaf(lsum, alpha, ps);
#pragma unroll
        for (int r = 0; r < 16; ++r) { O0[r] *= alpha; O1[r] *= alpha; }

        unsigned pk[8];
#pragma unroll
        for (int hh = 0; hh < 8; ++hh) {
            auto pr = __builtin_amdgcn_cvt_pkrtz(p[2 * hh], p[2 * hh + 1]);
            unsigned pu; __builtin_memcpy(&pu, &pr, 4);
            pk[hh] = pu;
        }
#pragma unroll
        for (int s = 0; s < 2; ++s) {       // C-frag -> B-frag(P^T): lane^32 swap
            unsigned send0 = lh ? pk[4 * s + 0] : pk[4 * s + 2];
            unsigned send1 = lh ? pk[4 * s + 1] : pk[4 * s + 3];
            unsigned r0 = (unsigned)__shfl_xor((int)send0, 32);
            unsigned r1 = (unsigned)__shfl_xor((int)send1, 32);
            H8U4 pb;
            pb.u[0] = lh ? r0 : pk[4 * s + 0];
            pb.u[1] = lh ? r1 : pk[4 * s + 1];
            pb.u[2] = lh ? pk[4 * s + 2] : r0;
            pb.u[3] = lh ? pk[4 * s + 3] : r1;
            O0 = __builtin_amdgcn_mfma_f32_32x32x16_f16(vf[s], pb.v, O0, 0, 0, 0);
            O1 = __builtin_amdgcn_mfma_f32_32x32x16_f16(vf[2 + s], pb.v, O1, 0, 0, 0);
        }
    };

    // rotated 2-deep register pipeline (no dynamic reg indexing)
    h8 kfA[4], vfA[4]; float4 hrA[4];
    h8 kfB[4], vfB[4]; float4 hrB[4];
    loadT(0, kfA, vfA, hrA);
    int jj = 0;
    while (true) {
        if (jj < jmax) loadT(jj + 1, kfB, vfB, hrB);
        comp(jj, kfA, vfA, hrA);
        if (++jj > jmax) break;
        if (jj < jmax) loadT(jj + 1, kfA, vfA, hrA);
        comp(jj, kfB, vfB, hrB);
        if (++jj > jmax) break;
    }

    // epilogue: l = own + partner(lane^32); normalized float4 stores
    float lt = lsum + __shfl_xor(lsum, 32);
    float inv = 1.f / lt;
    size_t ro = fbase + (size_t)qrow * DD;
#pragma unroll
    for (int g = 0; g < 4; ++g) {
        float4 o0 = make_float4(O0[4 * g + 0] * inv, O0[4 * g + 1] * inv,
                                O0[4 * g + 2] * inv, O0[4 * g + 3] * inv);
        *(float4*)&out[ro + 8 * g + 4 * lh] = o0;
        float4 o1 = make_float4(O1[4 * g + 0] * inv, O1[4 * g + 1] * inv,
                                O1[4 * g + 2] * inv, O1[4 * g + 3] * inv);
        *(float4*)&out[ro + 32 + 8 * g + 4 * lh] = o1;
    }
}

extern "C" void kernel_launch(void* const* d_in, const int* in_sizes, int n_in,
                              void* d_out, int out_size, void* d_ws, size_t ws_size,
                              hipStream_t stream) {
    (void)in_sizes; (void)n_in; (void)out_size; (void)ws_size;
    const float* q = (const float*)d_in[0];
    const float* k = (const float*)d_in[1];
    const float* v = (const float*)d_in[2];
    float* out = (float*)d_out;

    // ws: [hk 256KB][Ks 8MB f16][Vs 8MB f16]
    float* hk = (float*)d_ws;
    _Float16* Ks = (_Float16*)((char*)d_ws + 262144);
    _Float16* Vs = (_Float16*)((char*)d_ws + 262144 + 8388608);

    prep<<<dim3(64, 32), 64, 0, stream>>>(k, v, Ks, Vs, hk);
    rbf_attn<<<dim3(32, 32), 128, 0, stream>>>(q, Ks, Vs, hk, out);
}